// Round 4
// baseline (109.401 us; speedup 1.0000x reference)
//
#include <hip/hip_runtime.h>

#define EPS 1e-4f

constexpr int B  = 8;
constexpr int C  = 128;
constexpr int Tt = 9;
constexpr int T  = 8;
constexpr int H  = 64;
constexpr int W  = 64;
constexpr int HW = H * W;          // 4096
constexpr int HM = 256;
constexpr int WM = 256;
constexpr int HWM = HM * WM;       // 65536

typedef __attribute__((ext_vector_type(4))) float f32x4;

// ws layout (float offsets). Every cell is written before read on every
// replay — no cross-replay state, no zero-init needed.
constexpr int WS_TV  = 0;                      // B*HW      = 32768
constexpr int WS_RV  = WS_TV + B * HW;         // B*T*HW    = 262144
constexpr int WS_GSP = WS_RV + B * T * HW;     // gs partials [b][c2][t] = 8*64*8
constexpr int WS_VSP = WS_GSP + B * 64 * T;    // vs partials [b][t] = 64

__device__ __forceinline__ const f32x4& ld4(const float* p) {
  return *reinterpret_cast<const f32x4*>(p);
}
__device__ __forceinline__ void st4(float* p, f32x4 v) {
  *reinterpret_cast<f32x4*>(p) = v;
}

// --- antialiased bilinear downsample 256 -> 64 (scale 1/4), one output pixel.
// jax.image.resize 'bilinear' antialias=True: sample = 4o+1.5, taps 4o-2..4o+5,
// unnormalized weights {1,3,5,7,7,5,3,1}, per-dim renormalized over valid taps.
__device__ __forceinline__ float resample_px(const float* __restrict__ src,
                                             int y, int x) {
  const float wt[8] = {1.f, 3.f, 5.f, 7.f, 7.f, 5.f, 3.f, 1.f};
  int by = 4 * y - 2, bx = 4 * x - 2;
  float wx[8];
  float nx = 0.f;
  #pragma unroll
  for (int d = 0; d < 8; ++d) {
    int xx = bx + d;
    float w = (xx >= 0 && xx < WM) ? wt[d] : 0.f;
    wx[d] = w;
    nx += w;
  }
  float ny = 0.f;
  float sum = 0.f;
  #pragma unroll
  for (int dy = 0; dy < 8; ++dy) {
    int yy = by + dy;
    if (yy < 0 || yy >= HM) continue;
    ny += wt[dy];
    const float* row = src + yy * WM;
    float rowsum = 0.f;
    #pragma unroll
    for (int dx = 0; dx < 8; ++dx) {
      int xx = bx + dx;
      xx = xx < 0 ? 0 : (xx >= WM ? WM - 1 : xx);  // clamp addr; weight 0 if OOB
      rowsum += wx[dx] * row[xx];
    }
    sum += wt[dy] * rowsum;
  }
  return sum / (ny * nx);
}

// Kernel A: masks, grid-strided over all 72 maps * 4096 px.
__global__ __launch_bounds__(256) void mask_kernel(
    const float* __restrict__ tvmap, const float* __restrict__ rvmaps,
    float* __restrict__ ws) {
  int gtid = blockIdx.x * 256 + threadIdx.x;
  constexpr int TOTAL = (B + B * T) * HW;  // 294912
  for (int p = gtid; p < TOTAL; p += 512 * 256) {
    int m = p >> 12;          // map index 0..71
    int px = p & (HW - 1);
    int y = px >> 6, x = px & 63;
    const float* src;
    float* dst;
    if (m < B) {
      src = tvmap + (size_t)m * HWM;
      dst = ws + WS_TV + m * HW;
    } else {
      src = rvmaps + (size_t)(m - B) * HWM;
      dst = ws + WS_RV + (m - B) * HW;
    }
    float v = resample_px(src, y, x);
    dst[px] = (v > 0.5f) ? 1.f : 0.f;
  }
}

// Kernel B: gs partials. Each block owns 2 whole channels of one b —
// fully contiguous 2x147KB read stream. grid = b(8) x c2(64) = 512 blocks,
// 512 threads (16 waves/CU).
__global__ __launch_bounds__(512, 4) void gs_kernel(
    const float* __restrict__ values, float* __restrict__ ws) {
  int bid = blockIdx.x;
  int c2 = bid & 63, b = bid >> 6;
  int tid = threadIdx.x;

  float acc[T];
  #pragma unroll
  for (int t = 0; t < T; ++t) acc[t] = 0.f;
  float vsa[T];
  #pragma unroll
  for (int t = 0; t < T; ++t) vsa[t] = 0.f;

  const float* vb = values + (size_t)(b * C + c2 * 2) * Tt * HW;

  #pragma unroll
  for (int pq = 0; pq < 2; ++pq) {
    int px = pq * 2048 + tid * 4;
    f32x4 tv = ld4(ws + WS_TV + b * HW + px);
    f32x4 vm[T];
    #pragma unroll
    for (int t = 0; t < T; ++t)
      vm[t] = tv * ld4(ws + WS_RV + (b * T + t) * HW + px);
    if (c2 == 0) {
      #pragma unroll
      for (int t = 0; t < T; ++t)
        vsa[t] += vm[t][0] + vm[t][1] + vm[t][2] + vm[t][3];
    }
    #pragma unroll
    for (int ci = 0; ci < 2; ++ci) {
      const float* vc = vb + (size_t)ci * Tt * HW;
      f32x4 tf = ld4(vc + px);
      #pragma unroll
      for (int t = 0; t < T; ++t) {
        f32x4 rf = ld4(vc + (t + 1) * HW + px);
        #pragma unroll
        for (int j = 0; j < 4; ++j) acc[t] += tf[j] * rf[j] * vm[t][j];
      }
    }
  }

  __shared__ float red[8][T];
  int lane = tid & 63, wave = tid >> 6;
  #pragma unroll
  for (int t = 0; t < T; ++t) {
    float v = acc[t];
    #pragma unroll
    for (int m = 32; m > 0; m >>= 1) v += __shfl_xor(v, m);
    if (lane == 0) red[wave][t] = v;
  }
  __syncthreads();
  if (tid < T) {
    float s = 0.f;
    #pragma unroll
    for (int w = 0; w < 8; ++w) s += red[w][tid];
    ws[WS_GSP + bid * T + tid] = s;     // bid = b*64 + c2
  }

  if (c2 == 0) {
    __syncthreads();
    #pragma unroll
    for (int t = 0; t < T; ++t) {
      float v = vsa[t];
      #pragma unroll
      for (int m = 32; m > 0; m >>= 1) v += __shfl_xor(v, m);
      if (lane == 0) red[wave][t] = v;
    }
    __syncthreads();
    if (tid < T) {
      float s = 0.f;
      #pragma unroll
      for (int w = 0; w < 8; ++w) s += red[w][tid];
      ws[WS_VSP + b * T + tid] = s;
    }
  }
}

// Kernel C: finalize gs (redundant, tiny) + per-px softmax + t_feat copy +
// c_out + c_mask. Same block geometry as B: 512 blocks x 512 thr, contiguous.
__global__ __launch_bounds__(512, 4) void out_kernel(
    const float* __restrict__ values, const float* __restrict__ ws,
    float* __restrict__ out) {
  int bid = blockIdx.x;
  int c2 = bid & 63, b = bid >> 6;
  int tid = threadIdx.x;

  __shared__ float gsf_sh[T];
  if (tid < 64) {
    int t = tid >> 3, part = tid & 7;
    float s = 0.f;
    #pragma unroll
    for (int k = 0; k < 8; ++k)
      s += ws[WS_GSP + (b * 64 + part * 8 + k) * T + t];
    #pragma unroll
    for (int m = 1; m < 8; m <<= 1) s += __shfl_xor(s, m);
    if (part == 0) {
      float vs = ws[WS_VSP + b * T + t];  // exact integer-valued count
      bool zero = vs < EPS;
      float g = zero ? 0.f : s;
      vs += zero ? 1.f : 0.f;
      gsf_sh[t] = g / vs / (float)C;
    }
  }
  __syncthreads();

  float gsf[T];
  #pragma unroll
  for (int t = 0; t < T; ++t) gsf[t] = gsf_sh[t];

  const float* vb = values + (size_t)(b * C + c2 * 2) * Tt * HW;

  #pragma unroll
  for (int pq = 0; pq < 2; ++pq) {
    int px = pq * 2048 + tid * 4;

    f32x4 rv[T], cm[T];
    #pragma unroll
    for (int t = 0; t < T; ++t)
      rv[t] = ld4(ws + WS_RV + (b * T + t) * HW + px);

    // masked_vec = gsf*rv (zeros where rv=0 participate in the max)
    f32x4 mx = gsf[0] * rv[0];
    #pragma unroll
    for (int t = 1; t < T; ++t) {
      #pragma unroll
      for (int j = 0; j < 4; ++j) mx[j] = fmaxf(mx[j], gsf[t] * rv[t][j]);
    }
    f32x4 s = {0.f, 0.f, 0.f, 0.f};
    #pragma unroll
    for (int t = 0; t < T; ++t) {
      #pragma unroll
      for (int j = 0; j < 4; ++j)
        cm[t][j] = expf(gsf[t] * rv[t][j] - mx[j]) * rv[t][j];
      s += cm[t];
    }
    #pragma unroll
    for (int j = 0; j < 4; ++j) {
      s[j] += (s[j] < EPS) ? 1.f : 0.f;
      s[j] = 1.f / s[j];
    }
    f32x4 csum = {0.f, 0.f, 0.f, 0.f};
    #pragma unroll
    for (int t = 0; t < T; ++t) {
      cm[t] *= s;
      csum += cm[t];
    }

    if (c2 == 0) {
      f32x4 cmask;
      #pragma unroll
      for (int j = 0; j < 4; ++j) cmask[j] = 1.f - csum[j];
      st4(out + ((size_t)b * 257 + 256) * HW + px, cmask);
      st4(out + (size_t)B * 257 * HW + (size_t)b * HW + px, cmask);
    }

    #pragma unroll
    for (int ci = 0; ci < 2; ++ci) {
      const float* vc = vb + (size_t)ci * Tt * HW;
      f32x4 tf = ld4(vc + px);
      st4(out + ((size_t)b * 257 + c2 * 2 + ci) * HW + px, tf);  // t_feat
      f32x4 acc = {0.f, 0.f, 0.f, 0.f};
      #pragma unroll
      for (int t = 0; t < T; ++t) {
        f32x4 rf = ld4(vc + (t + 1) * HW + px);
        acc += rf * cm[t];
      }
      st4(out + ((size_t)b * 257 + 128 + c2 * 2 + ci) * HW + px, acc);
    }
  }
}

extern "C" void kernel_launch(void* const* d_in, const int* in_sizes, int n_in,
                              void* d_out, int out_size, void* d_ws, size_t ws_size,
                              hipStream_t stream) {
  const float* values = (const float*)d_in[0];
  const float* tvmap  = (const float*)d_in[1];
  const float* rvmaps = (const float*)d_in[2];
  float* out = (float*)d_out;
  float* ws  = (float*)d_ws;

  hipLaunchKernelGGL(mask_kernel, dim3(512), dim3(256), 0, stream,
                     tvmap, rvmaps, ws);
  hipLaunchKernelGGL(gs_kernel, dim3(512), dim3(512), 0, stream,
                     values, ws);
  hipLaunchKernelGGL(out_kernel, dim3(512), dim3(512), 0, stream,
                     values, ws, out);
}